// Round 9
// baseline (662.023 us; speedup 1.0000x reference)
//
#include <hip/hip_runtime.h>
#include <cstdint>
#include <cmath>

#define BATCH 64

typedef __attribute__((ext_vector_type(8))) __bf16 bf16x8;
typedef __attribute__((ext_vector_type(16))) float f32x16;

// ---------------------------------------------------------------------------
// Spline + silu expansion: x -> [silu(x), B_0(x) .. B_7(x)]
// ---------------------------------------------------------------------------
__device__ __forceinline__ void expand9(float x, float* e) {
  float t = __expf(-x);
  e[0] = __fdividef(x, 1.f + t);  // silu
  float b[11];
#pragma unroll
  for (int j = 0; j < 11; ++j) {
    float gj  = 0.4f * (float)j - 2.2f;
    float gj1 = 0.4f * (float)(j + 1) - 2.2f;
    b[j] = (x >= gj && x < gj1) ? 1.f : 0.f;
  }
#pragma unroll
  for (int k = 1; k <= 3; ++k) {
    float inv = 1.f / (0.4f * (float)k);
#pragma unroll
    for (int j = 0; j < 11 - k; ++j) {
      float gj   = 0.4f * (float)j - 2.2f;
      float gjk1 = 0.4f * (float)(j + k + 1) - 2.2f;
      b[j] = ((x - gj) * b[j] + (gjk1 - x) * b[j + 1]) * inv;
    }
  }
#pragma unroll
  for (int v = 0; v < 8; ++v) e[v + 1] = b[v];
}

// bf16 split helpers (round-to-nearest-even)
__device__ __forceinline__ unsigned short f2bf(float x) {
  uint32_t u = __float_as_uint(x);
  uint32_t r = u + 0x7fffu + ((u >> 16) & 1u);
  return (unsigned short)(r >> 16);
}
__device__ __forceinline__ float bf2f(unsigned short h) {
  return __uint_as_float(((uint32_t)h) << 16);
}
__device__ __forceinline__ uint32_t packsplit(float x) {
  unsigned short hi = f2bf(x);
  unsigned short lo = f2bf(x - bf2f(hi));
  return (uint32_t)hi | ((uint32_t)lo << 16);
}

// ---------------------------------------------------------------------------
// h = relu(x @ lin_w^T + lin_b); also writes packed expansion E (main path)
// ---------------------------------------------------------------------------
__global__ __launch_bounds__(256) void linear_pack_kernel(
    const float* __restrict__ x, const float* __restrict__ w,
    const float* __restrict__ bias, float* __restrict__ h,
    uint32_t* __restrict__ E, int writeE) {
  int idx = blockIdx.x * 256 + threadIdx.x;  // 64*2048
  int b = idx >> 11, o = idx & 2047;
  const float* xr = x + b * 100;
  const float* wr = w + o * 100;
  float acc = bias[o];
#pragma unroll 4
  for (int k = 0; k < 100; ++k) acc += xr[k] * wr[k];
  float hv = fmaxf(acc, 0.f);
  h[idx] = hv;
  if (writeE) {
    float e[9];
    expand9(hv, e);
    uint32_t* p = E + (size_t)idx * 9;
#pragma unroll
    for (int v = 0; v < 9; ++v) p[v] = packsplit(e[v]);
  }
}

// ---------------------------------------------------------------------------
// Pack expanded weights into MFMA-staging layout:
// Bg[kc][plane(hi=0,lo=1)][v(9)][n(N)][fl(16)]  (bf16)
// ---------------------------------------------------------------------------
template <int F, int N>
__global__ __launch_bounds__(256) void prep_bpack(
    const float* __restrict__ bw, const float* __restrict__ sw,
    const float* __restrict__ ss, unsigned short* __restrict__ Bg) {
  int idx = blockIdx.x * 256 + threadIdx.x;  // over (F/16)*9*N*16
  int fl = idx & 15;
  int n = (idx >> 4) & (N - 1);
  int rest = idx >> 4;
  rest /= N;
  int v = rest % 9;
  int kc = rest / 9;
  int f = kc * 16 + fl;
  size_t src = (size_t)n * F + f;
  float wv = (v == 0) ? bw[src] : sw[src * 8 + (v - 1)] * ss[src];
  unsigned short hi = f2bf(wv);
  unsigned short lo = f2bf(wv - bf2f(hi));
  size_t base = ((size_t)kc * 2 * 9 + v) * N * 16 + (size_t)n * 16 + fl;
  Bg[base] = hi;                          // plane 0
  Bg[base + (size_t)9 * N * 16] = lo;     // plane 1
}

// ---------------------------------------------------------------------------
// Split-bf16 MFMA GEMM over expanded basis (round-6 proven).
// ---------------------------------------------------------------------------
template <int CIN, int COUT, int HO, int WO, int SK>
__global__ __launch_bounds__(256, 2) void gemm_mfma(
    const uint32_t* __restrict__ E, const unsigned short* __restrict__ Bg,
    float* __restrict__ part) {
  constexpr int F = CIN * 9;
  constexpr int NKC = F / 16;
  constexpr int HI = HO / 2, WI = WO / 2;
  constexpr int M = BATCH * HO * WO;
  constexpr int CPB = NKC / SK;
  static_assert(NKC % SK == 0, "sk");

  __shared__ __align__(16) unsigned short lds[4 * 9216];

  const int t = threadIdx.x;
  const int mbase = blockIdx.x * 64;
  const int nb = blockIdx.y;
  const int kc0 = blockIdx.z * CPB;

  uint32_t ez[9];
  {
    float e0[9];
    expand9(0.f, e0);
#pragma unroll
    for (int v = 0; v < 9; ++v) ez[v] = packsplit(e0[v]);
  }

  const int lane = t & 63, wv_ = t >> 6;
  const int wm = wv_ >> 1, wn = wv_ & 1;
  const int frow = lane & 31, fkg = lane >> 5;
  const int aoff = ((wm * 32 + frow) * 16 + fkg * 8) * 2;  // bytes
  const int boff = ((wn * 32 + frow) * 16 + fkg * 8) * 2;

  f32x16 acc;
#pragma unroll
  for (int i = 0; i < 16; ++i) acc[i] = 0.f;

  for (int ci = 0; ci < CPB; ++ci) {
    const int kc = kc0 + ci;
    __syncthreads();

    // ---- stage A: 64 m x 16 fl ----
#pragma unroll
    for (int i = 0; i < 4; ++i) {
      int task = i * 256 + t;
      int ml = task >> 4, fl = task & 15;
      int f = kc * 16 + fl;
      int c = f / 9, r = f - 9 * c;
      int kh = r / 3, kw = r - kh * 3;
      int m = mbase + ml;
      int b = m / (HO * WO), hw2 = m % (HO * WO);
      int hh = hw2 / WO, ww = hw2 % WO;
      int hp = hh + kh - 1, wp = ww + kw - 1;
      bool ok = (unsigned)hp < (unsigned)HO && (unsigned)wp < (unsigned)WO;
      uint32_t uv[9];
      if (ok) {
        const uint32_t* ep =
            E + (size_t)(((b * CIN + c) * HI + (hp >> 1)) * WI + (wp >> 1)) * 9;
#pragma unroll
        for (int v = 0; v < 9; ++v) uv[v] = ep[v];
      } else {
#pragma unroll
        for (int v = 0; v < 9; ++v) uv[v] = ez[v];
      }
      int base = ml * 16 + fl;
#pragma unroll
      for (int v = 0; v < 9; ++v) {
        lds[v * 1024 + base] = (unsigned short)(uv[v] & 0xffffu);
        lds[9216 + v * 1024 + base] = (unsigned short)(uv[v] >> 16);
      }
    }

    // ---- stage B: linear copy ----
    {
      const unsigned short* bsrc = Bg + (size_t)kc * (2 * 9 * COUT * 16);
#pragma unroll
      for (int g = 0; g < 9; ++g) {
        int u = g * 256 + t;
        int pl = (u >= 1152) ? 1 : 0;
        int rr = u - pl * 1152;
        int v = rr >> 7, q = rr & 127;
        int nl = q >> 1, half = q & 1;
        size_t srcE = (size_t)pl * (9 * COUT * 16) + (size_t)v * (COUT * 16) +
                      (size_t)(nb * 64 + nl) * 16 + half * 8;
        int dst = (2 + pl) * 9216 + v * 1024 + nl * 16 + half * 8;
        *reinterpret_cast<float4*>(&lds[dst]) =
            *reinterpret_cast<const float4*>(&bsrc[srcE]);
      }
    }
    __syncthreads();

    // ---- compute: 9 v-steps x 3 split-products ----
#pragma unroll
    for (int v = 0; v < 9; ++v) {
      const char* lb = reinterpret_cast<const char*>(lds);
      bf16x8 ah = *reinterpret_cast<const bf16x8*>(lb + v * 2048 + aoff);
      bf16x8 al = *reinterpret_cast<const bf16x8*>(lb + 18432 + v * 2048 + aoff);
      bf16x8 bh = *reinterpret_cast<const bf16x8*>(lb + 36864 + v * 2048 + boff);
      bf16x8 bl = *reinterpret_cast<const bf16x8*>(lb + 55296 + v * 2048 + boff);
      acc = __builtin_amdgcn_mfma_f32_32x32x16_bf16(ah, bh, acc, 0, 0, 0);
      acc = __builtin_amdgcn_mfma_f32_32x32x16_bf16(ah, bl, acc, 0, 0, 0);
      acc = __builtin_amdgcn_mfma_f32_32x32x16_bf16(al, bh, acc, 0, 0, 0);
    }
  }

  float* p = part + (size_t)blockIdx.z * M * COUT;
  const int gn = nb * 64 + wn * 32 + frow;
#pragma unroll
  for (int r = 0; r < 16; ++r) {
    int mlocal = (r & 3) + 8 * (r >> 2) + 4 * fkg;
    int gm = mbase + wm * 32 + mlocal;
    p[(size_t)gm * COUT + gn] = acc[r];
  }
}

// ---------------------------------------------------------------------------
template <int COUT, int HO, int WO>
__global__ __launch_bounds__(256) void reduce_pe_pack(
    const float* __restrict__ part, uint32_t* __restrict__ E, int SK) {
  constexpr int M = BATCH * HO * WO;
  int idx = blockIdx.x * 256 + threadIdx.x;
  int ww = idx % WO;
  int tmp = idx / WO;
  int hh = tmp % HO;
  tmp /= HO;
  int o = tmp % COUT;
  int b = tmp / COUT;
  int m = (b * HO + hh) * WO + ww;
  float s = 0.f;
  for (int k = 0; k < SK; ++k) s += part[((size_t)k * M + m) * COUT + o];
  float e[9];
  expand9(s, e);
  uint32_t* p = E + (size_t)idx * 9;
#pragma unroll
  for (int v = 0; v < 9; ++v) p[v] = packsplit(e[v]);
}

template <int COUT, int HO, int WO>
__global__ __launch_bounds__(256) void reduce_p(
    const float* __restrict__ part, float* __restrict__ act, int SK) {
  constexpr int M = BATCH * HO * WO;
  int idx = blockIdx.x * 256 + threadIdx.x;
  int ww = idx % WO;
  int tmp = idx / WO;
  int hh = tmp % HO;
  tmp /= HO;
  int o = tmp % COUT;
  int b = tmp / COUT;
  int m = (b * HO + hh) * WO + ww;
  float s = 0.f;
  for (int k = 0; k < SK; ++k) s += part[((size_t)k * M + m) * COUT + o];
  act[idx] = s;
}

// ---------------------------------------------------------------------------
// L4 v6: fused LDS expansion + NEIGHBOR-PRE-SUMMED weights.
// For a fixed output parity class (PH,PW), every tap (kh,kw) maps to one of
// 4 input neighbors (a=(kh>PH), b2=(kw>PW)); taps sharing a neighbor share
// the same input (incl. the padded-zero case), so their weights pre-sum
// exactly: Wn[c][pc][nb][v][o] = sum_{taps->nb} W[o,c,kh,kw,v].
// FMA count drops 9 taps -> 4 neighbors (2.25x); weight loads are scalar
// (compile-time indices off a block-uniform base).
// ---------------------------------------------------------------------------
__global__ __launch_bounds__(256) void prep_wnl4(
    const float* __restrict__ bw, const float* __restrict__ sw,
    const float* __restrict__ ss, float* __restrict__ Wn) {
  int idx = blockIdx.x * 256 + threadIdx.x;  // 64*4*4*27 = 27648
  if (idx >= 27648) return;
  int u = idx % 27;
  int o = u % 3, v = u / 3;
  int rest = idx / 27;
  int nb = rest & 3;
  rest >>= 2;
  int pc = rest & 3;
  rest >>= 2;
  int c = rest;  // 0..63
  int PH = pc >> 1, PW = pc & 1;
  int a = nb >> 1, b2 = nb & 1;
  float s = 0.f;
#pragma unroll
  for (int kh = 0; kh < 3; ++kh) {
    if (((kh > PH) ? 1 : 0) != a) continue;
#pragma unroll
    for (int kw = 0; kw < 3; ++kw) {
      if (((kw > PW) ? 1 : 0) != b2) continue;
      int f = c * 9 + kh * 3 + kw;
      float wv = (v == 0)
                     ? bw[o * 576 + f]
                     : sw[((size_t)(o * 576 + f)) * 8 + (v - 1)] * ss[o * 576 + f];
      s += wv;
    }
  }
  Wn[idx] = s;
}

template <int PH, int PW>
__device__ void l4v6_wave(const float* __restrict__ eLds,
                          const float* __restrict__ WnB,
                          const float* __restrict__ ez, int lane, int bb,
                          int cs, float* __restrict__ p4) {
  constexpr int PC = PH * 2 + PW;
  const int j = lane & 15;
  const int i0 = (lane >> 4) << 2;
  float acc[4][3] = {};
#pragma unroll
  for (int cl = 0; cl < 4; ++cl) {
#pragma unroll
    for (int nb = 0; nb < 4; ++nb) {
      const int a = nb >> 1, b2 = nb & 1;
      const float* wp = WnB + ((cl * 4 + PC) * 4 + nb) * 27;
      float w27[27];
#pragma unroll
      for (int u = 0; u < 27; ++u) w27[u] = wp[u];
#pragma unroll
      for (int q = 0; q < 4; ++q) {
        const int gi = i0 + q + PH - 1 + a;
        const int gj = j + PW - 1 + b2;
        const bool ok = ((unsigned)gi < 16u) && ((unsigned)gj < 16u);
        const int pp = ok ? (gi * 16 + gj) : 0;
        const float* ep = eLds + cl * 2304 + pp * 9;
        float en[9];
#pragma unroll
        for (int v = 0; v < 9; ++v) en[v] = ok ? ep[v] : ez[v];
#pragma unroll
        for (int v = 0; v < 9; ++v) {
          acc[q][0] = fmaf(en[v], w27[v * 3 + 0], acc[q][0]);
          acc[q][1] = fmaf(en[v], w27[v * 3 + 1], acc[q][1]);
          acc[q][2] = fmaf(en[v], w27[v * 3 + 2], acc[q][2]);
        }
      }
    }
  }
#pragma unroll
  for (int q = 0; q < 4; ++q) {
    const int h = ((i0 + q) << 1) + PH, w = (j << 1) + PW;
#pragma unroll
    for (int o = 0; o < 3; ++o)
      p4[(size_t)cs * 196608 + ((bb * 3 + o) << 10) + (h << 5) + w] = acc[q][o];
  }
}

__global__ __launch_bounds__(256) void kan_l4_v6(
    const float* __restrict__ a3, const float* __restrict__ Wn,
    float* __restrict__ p4) {
  __shared__ float eLds[4 * 256 * 9];  // 36.9 KB
  const int bid = blockIdx.x;          // 64 bb x 16 cs
  const int bb = bid >> 4, cs = bid & 15;
  const int t = threadIdx.x;
  float ez[9];
  expand9(0.f, ez);
  // stage: expand 4 channels x 256 pixels (1 pixel/thread/channel)
#pragma unroll
  for (int cl = 0; cl < 4; ++cl) {
    float x = a3[(size_t)(bb * 64 + cs * 4 + cl) * 256 + t];
    float ev[9];
    expand9(x, ev);
#pragma unroll
    for (int v = 0; v < 9; ++v) eLds[(cl * 256 + t) * 9 + v] = ev[v];
  }
  __syncthreads();
  const int wv_ = t >> 6, lane = t & 63;
  const float* WnB = Wn + (size_t)cs * 4 * (4 * 4 * 27);
  if (wv_ == 0)
    l4v6_wave<0, 0>(eLds, WnB, ez, lane, bb, cs, p4);
  else if (wv_ == 1)
    l4v6_wave<0, 1>(eLds, WnB, ez, lane, bb, cs, p4);
  else if (wv_ == 2)
    l4v6_wave<1, 0>(eLds, WnB, ez, lane, bb, cs, p4);
  else
    l4v6_wave<1, 1>(eLds, WnB, ez, lane, bb, cs, p4);
}

__global__ __launch_bounds__(256) void reduce_tanh_l4_16(
    const float* __restrict__ p4, float* __restrict__ out) {
  int i = blockIdx.x * 256 + threadIdx.x;  // 196608
  float s = 0.f;
#pragma unroll
  for (int k = 0; k < 16; ++k) s += p4[(size_t)k * 196608 + i];
  out[i] = tanhf(s);
}

__global__ __launch_bounds__(256) void reduce_tanh_l4(
    const float* __restrict__ p4, float* __restrict__ out) {
  int i = blockIdx.x * 256 + threadIdx.x;
  float s = p4[i] + p4[i + 196608] + p4[i + 2 * 196608] + p4[i + 3 * 196608];
  out[i] = tanhf(s);
}

// ---------------------------------------------------------------------------
// Fallback path (round-1 proven) for small workspace
// ---------------------------------------------------------------------------
template <int CIN, int COUT, int HO, int WO, int BN, int SK>
__global__ __launch_bounds__(256) void kan_gemm(
    const float* __restrict__ in, const float* __restrict__ bw,
    const float* __restrict__ sw, const float* __restrict__ ss,
    float* __restrict__ outp) {
  constexpr int BM = 64, TM = 4, TN = 4, FC = 16;
  constexpr int F = CIN * 9;
  constexpr int HI = HO / 2, WI = WO / 2;
  constexpr int M = BATCH * HO * WO;
  constexpr int FPB = F / SK;

  __shared__ float Ae[FC * 9][BM];

  const int t = threadIdx.x;
  const int mbase = blockIdx.x * BM;
  const int obase = blockIdx.y * BN;
  const int f0 = blockIdx.z * FPB;

  const int cg = t & (BN / TN - 1);
  const int rg = t / (BN / TN);
  const int m0 = rg * TM;
  const int o0 = obase + cg * TN;

  float acc[TM][TN] = {};

  for (int fc = f0; fc < f0 + FPB; fc += FC) {
#pragma unroll
    for (int j = 0; j < BM * FC / 256; ++j) {
      int p = j * 256 + t;
      int ml = p & (BM - 1);
      int df = p >> 6;
      int f = fc + df;
      int c = f / 9;
      int r = f - c * 9;
      int kh = r / 3, kw = r - kh * 3;
      int m = mbase + ml;
      int bb = m / (HO * WO);
      int rem = m % (HO * WO);
      int hh = rem / WO, ww = rem % WO;
      int hp = hh + kh - 1, wp = ww + kw - 1;
      float val = 0.f;
      if (hp >= 0 && hp < HO && wp >= 0 && wp < WO)
        val = in[((bb * CIN + c) * HI + (hp >> 1)) * WI + (wp >> 1)];
      float e[9];
      expand9(val, e);
#pragma unroll
      for (int v = 0; v < 9; ++v) Ae[df * 9 + v][ml] = e[v];
    }
    __syncthreads();

#pragma unroll 2
    for (int df = 0; df < FC; ++df) {
      int f = fc + df;
      float wb[TN], wsv[TN][8];
#pragma unroll
      for (int tn = 0; tn < TN; ++tn) {
        int i = (o0 + tn) * F + f;
        wb[tn] = bw[i];
        float sc = ss[i];
        const float4* sp = reinterpret_cast<const float4*>(sw + (size_t)i * 8);
        float4 s0 = sp[0], s1 = sp[1];
        wsv[tn][0] = s0.x * sc; wsv[tn][1] = s0.y * sc;
        wsv[tn][2] = s0.z * sc; wsv[tn][3] = s0.w * sc;
        wsv[tn][4] = s1.x * sc; wsv[tn][5] = s1.y * sc;
        wsv[tn][6] = s1.z * sc; wsv[tn][7] = s1.w * sc;
      }
      float a[9][TM];
#pragma unroll
      for (int v = 0; v < 9; ++v) {
        float4 q = *reinterpret_cast<const float4*>(&Ae[df * 9 + v][m0]);
        a[v][0] = q.x; a[v][1] = q.y; a[v][2] = q.z; a[v][3] = q.w;
      }
#pragma unroll
      for (int tm = 0; tm < TM; ++tm)
#pragma unroll
        for (int tn = 0; tn < TN; ++tn) acc[tm][tn] += a[0][tm] * wb[tn];
#pragma unroll
      for (int v = 1; v < 9; ++v)
#pragma unroll
        for (int tm = 0; tm < TM; ++tm)
#pragma unroll
          for (int tn = 0; tn < TN; ++tn)
            acc[tm][tn] += a[v][tm] * wsv[tn][v - 1];
    }
    __syncthreads();
  }

  if constexpr (SK > 1) {
    float* p = outp + (size_t)blockIdx.z * M * COUT;
#pragma unroll
    for (int tm = 0; tm < TM; ++tm) {
      int m = mbase + m0 + tm;
#pragma unroll
      for (int tn = 0; tn < TN; ++tn)
        p[(size_t)m * COUT + (o0 + tn)] = acc[tm][tn];
    }
  } else {
#pragma unroll
    for (int tm = 0; tm < TM; ++tm) {
      int m = mbase + m0 + tm;
      int bb = m / (HO * WO);
      int rem = m % (HO * WO);
      int hh = rem / WO, ww = rem % WO;
#pragma unroll
      for (int tn = 0; tn < TN; ++tn) {
        int o = o0 + tn;
        outp[((bb * COUT + o) * HO + hh) * WO + ww] = acc[tm][tn];
      }
    }
  }
}

template <int COUT, int HO, int WO, int SK>
__global__ __launch_bounds__(256) void reduce_partials_old(
    const float* __restrict__ part, float* __restrict__ act) {
  constexpr int M = BATCH * HO * WO;
  int idx = blockIdx.x * 256 + threadIdx.x;
  if (idx >= M * COUT) return;
  float s = 0.f;
#pragma unroll
  for (int k = 0; k < SK; ++k) s += part[(size_t)k * M * COUT + idx];
  int m = idx / COUT, o = idx - (idx / COUT) * COUT;
  int bb = m / (HO * WO);
  int rem = m % (HO * WO);
  int hh = rem / WO, ww = rem % WO;
  act[((bb * COUT + o) * HO + hh) * WO + ww] = s;
}

__global__ __launch_bounds__(256) void kan_l4_split(
    const float* __restrict__ a3, const float* __restrict__ bw,
    const float* __restrict__ sw, const float* __restrict__ ss,
    float* __restrict__ p4) {
  int tid = blockIdx.x * 256 + threadIdx.x;
  int cs = tid >> 16, pix = tid & 65535;
  int b = pix >> 10, rem = pix & 1023, h = rem >> 5, w = rem & 31;
  float acc[3] = {0.f, 0.f, 0.f};
  for (int c = cs * 16; c < cs * 16 + 16; ++c) {
#pragma unroll
    for (int kh = 0; kh < 3; ++kh) {
#pragma unroll
      for (int kw = 0; kw < 3; ++kw) {
        int f = (c * 3 + kh) * 3 + kw;
        int hp = h + kh - 1, wp = w + kw - 1;
        float x = 0.f;
        if ((unsigned)hp < 32u && (unsigned)wp < 32u)
          x = a3[((b * 64 + c) * 16 + (hp >> 1)) * 16 + (wp >> 1)];
        float e[9];
        expand9(x, e);
#pragma unroll
        for (int o = 0; o < 3; ++o) {
          int i = o * 576 + f;
          float d = e[1] * sw[i * 8 + 0];
#pragma unroll
          for (int v = 1; v < 8; ++v) d += e[v + 1] * sw[i * 8 + v];
          acc[o] += e[0] * bw[i] + d * ss[i];
        }
      }
    }
  }
#pragma unroll
  for (int o = 0; o < 3; ++o)
    p4[cs * 196608 + ((b * 3 + o) << 10) + (h << 5) + w] = acc[o];
}

// ---------------------------------------------------------------------------
extern "C" void kernel_launch(void* const* d_in, const int* in_sizes, int n_in,
                              void* d_out, int out_size, void* d_ws,
                              size_t ws_size, hipStream_t stream) {
  const float* x     = (const float*)d_in[0];
  const float* lin_w = (const float*)d_in[1];
  const float* lin_b = (const float*)d_in[2];
  const float* bw1 = (const float*)d_in[3];
  const float* sw1 = (const float*)d_in[4];
  const float* ss1 = (const float*)d_in[5];
  const float* bw2 = (const float*)d_in[6];
  const float* sw2 = (const float*)d_in[7];
  const float* ss2 = (const float*)d_in[8];
  const float* bw3 = (const float*)d_in[9];
  const float* sw3 = (const float*)d_in[10];
  const float* ss3 = (const float*)d_in[11];
  const float* bw4 = (const float*)d_in[12];
  const float* sw4 = (const float*)d_in[13];
  const float* ss4 = (const float*)d_in[14];

  float* wsf = (float*)d_ws;
  float* h  = wsf;                        // 131072
  float* a1 = h + 131072;                 // 262144 (fallback only)
  float* a2 = a1 + 262144;                // 524288 (fallback only)
  float* a3 = a2 + 524288;                // 1048576, ends at 1966080
  // main-path regions
  unsigned short* Bg = (unsigned short*)(wsf + 1966080);  // 10,616,832 float-slots
  float* part = wsf + 1966080 + 10616832;                 // 2,097,152
  uint32_t* Eg = (uint32_t*)(wsf + 14680064);             // 4,718,592
  float* wl4 = h;                    // h dead on main path after linear (27648 floats)
  float* p4  = wsf + 1966080;        // 16*196608 = 3.1M, reuses Bg (dead post-L3)

  const size_t baseFloats = 1966080;
  size_t availFloats = ws_size / 4 > baseFloats ? ws_size / 4 - baseFloats : 0;
  const size_t mainNeed = 10616832ull + 2097152ull + 4718592ull;  // 17.4M

  if (availFloats >= mainNeed) {
    linear_pack_kernel<<<512, 256, 0, stream>>>(x, lin_w, lin_b, h, Eg, 1);

    // L1: CIN=512 COUT=256 4x4, SK=8
    prep_bpack<4608, 256><<<41472, 256, 0, stream>>>(bw1, sw1, ss1, Bg);
    gemm_mfma<512, 256, 4, 4, 8>
        <<<dim3(16, 4, 8), 256, 0, stream>>>(Eg, Bg, part);
    reduce_pe_pack<256, 4, 4><<<1024, 256, 0, stream>>>(part, Eg, 8);

    // L2: CIN=256 COUT=128 8x8, SK=4
    prep_bpack<2304, 128><<<10368, 256, 0, stream>>>(bw2, sw2, ss2, Bg);
    gemm_mfma<256, 128, 8, 8, 4>
        <<<dim3(64, 2, 4), 256, 0, stream>>>(Eg, Bg, part);
    reduce_pe_pack<128, 8, 8><<<2048, 256, 0, stream>>>(part, Eg, 4);

    // L3: CIN=128 COUT=64 16x16, SK=2
    prep_bpack<1152, 64><<<2592, 256, 0, stream>>>(bw3, sw3, ss3, Bg);
    gemm_mfma<128, 64, 16, 16, 2>
        <<<dim3(256, 1, 2), 256, 0, stream>>>(Eg, Bg, part);
    reduce_p<64, 16, 16><<<4096, 256, 0, stream>>>(part, a3, 2);

    // L4: fused LDS expansion + neighbor-pre-summed weights + tanh reduce
    prep_wnl4<<<108, 256, 0, stream>>>(bw4, sw4, ss4, wl4);
    kan_l4_v6<<<1024, 256, 0, stream>>>(a3, wl4, p4);
    reduce_tanh_l4_16<<<768, 256, 0, stream>>>(p4, (float*)d_out);
  } else {
    // round-1 proven fallback (needs ~16.3 MB)
    float* partOld = a3 + 1048576;
    linear_pack_kernel<<<512, 256, 0, stream>>>(x, lin_w, lin_b, h, nullptr, 0);
    kan_gemm<512, 256, 4, 4, 64, 8>
        <<<dim3(16, 4, 8), 256, 0, stream>>>(h, bw1, sw1, ss1, partOld);
    reduce_partials_old<256, 4, 4, 8><<<1024, 256, 0, stream>>>(partOld, a1);
    kan_gemm<256, 128, 8, 8, 64, 2>
        <<<dim3(64, 2, 2), 256, 0, stream>>>(a1, bw2, sw2, ss2, partOld);
    reduce_partials_old<128, 8, 8, 2><<<2048, 256, 0, stream>>>(partOld, a2);
    kan_gemm<128, 64, 16, 16, 64, 1>
        <<<dim3(256, 1, 1), 256, 0, stream>>>(a2, bw3, sw3, ss3, a3);
    kan_l4_split<<<1024, 256, 0, stream>>>(a3, bw4, sw4, ss4, partOld);
    reduce_tanh_l4<<<768, 256, 0, stream>>>(partOld, (float*)d_out);
  }
}

// Round 10
// 530.507 us; speedup vs baseline: 1.2479x; 1.2479x over previous
//
#include <hip/hip_runtime.h>
#include <cstdint>
#include <cmath>

#define BATCH 64

typedef __attribute__((ext_vector_type(8))) __bf16 bf16x8;
typedef __attribute__((ext_vector_type(16))) float f32x16;

// ---------------------------------------------------------------------------
// Spline + silu expansion: x -> [silu(x), B_0(x) .. B_7(x)]
// ---------------------------------------------------------------------------
__device__ __forceinline__ void expand9(float x, float* e) {
  float t = __expf(-x);
  e[0] = __fdividef(x, 1.f + t);  // silu
  float b[11];
#pragma unroll
  for (int j = 0; j < 11; ++j) {
    float gj  = 0.4f * (float)j - 2.2f;
    float gj1 = 0.4f * (float)(j + 1) - 2.2f;
    b[j] = (x >= gj && x < gj1) ? 1.f : 0.f;
  }
#pragma unroll
  for (int k = 1; k <= 3; ++k) {
    float inv = 1.f / (0.4f * (float)k);
#pragma unroll
    for (int j = 0; j < 11 - k; ++j) {
      float gj   = 0.4f * (float)j - 2.2f;
      float gjk1 = 0.4f * (float)(j + k + 1) - 2.2f;
      b[j] = ((x - gj) * b[j] + (gjk1 - x) * b[j + 1]) * inv;
    }
  }
#pragma unroll
  for (int v = 0; v < 8; ++v) e[v + 1] = b[v];
}

// bf16 split helpers (round-to-nearest-even)
__device__ __forceinline__ unsigned short f2bf(float x) {
  uint32_t u = __float_as_uint(x);
  uint32_t r = u + 0x7fffu + ((u >> 16) & 1u);
  return (unsigned short)(r >> 16);
}
__device__ __forceinline__ float bf2f(unsigned short h) {
  return __uint_as_float(((uint32_t)h) << 16);
}
__device__ __forceinline__ uint32_t packsplit(float x) {
  unsigned short hi = f2bf(x);
  unsigned short lo = f2bf(x - bf2f(hi));
  return (uint32_t)hi | ((uint32_t)lo << 16);
}

// ---------------------------------------------------------------------------
// h = relu(x @ lin_w^T + lin_b); also writes packed expansion E (main path)
// ---------------------------------------------------------------------------
__global__ __launch_bounds__(256) void linear_pack_kernel(
    const float* __restrict__ x, const float* __restrict__ w,
    const float* __restrict__ bias, float* __restrict__ h,
    uint32_t* __restrict__ E, int writeE) {
  int idx = blockIdx.x * 256 + threadIdx.x;  // 64*2048
  int b = idx >> 11, o = idx & 2047;
  const float* xr = x + b * 100;
  const float* wr = w + o * 100;
  float acc = bias[o];
#pragma unroll 4
  for (int k = 0; k < 100; ++k) acc += xr[k] * wr[k];
  float hv = fmaxf(acc, 0.f);
  h[idx] = hv;
  if (writeE) {
    float e[9];
    expand9(hv, e);
    uint32_t* p = E + (size_t)idx * 9;
#pragma unroll
    for (int v = 0; v < 9; ++v) p[v] = packsplit(e[v]);
  }
}

// ---------------------------------------------------------------------------
// Pack expanded weights into MFMA-staging layout:
// Bg[kc][plane(hi=0,lo=1)][v(9)][n(N)][fl(16)]  (bf16)
// ---------------------------------------------------------------------------
template <int F, int N>
__global__ __launch_bounds__(256) void prep_bpack(
    const float* __restrict__ bw, const float* __restrict__ sw,
    const float* __restrict__ ss, unsigned short* __restrict__ Bg) {
  int idx = blockIdx.x * 256 + threadIdx.x;  // over (F/16)*9*N*16
  int fl = idx & 15;
  int n = (idx >> 4) & (N - 1);
  int rest = idx >> 4;
  rest /= N;
  int v = rest % 9;
  int kc = rest / 9;
  int f = kc * 16 + fl;
  size_t src = (size_t)n * F + f;
  float wv = (v == 0) ? bw[src] : sw[src * 8 + (v - 1)] * ss[src];
  unsigned short hi = f2bf(wv);
  unsigned short lo = f2bf(wv - bf2f(hi));
  size_t base = ((size_t)kc * 2 * 9 + v) * N * 16 + (size_t)n * 16 + fl;
  Bg[base] = hi;                          // plane 0
  Bg[base + (size_t)9 * N * 16] = lo;     // plane 1
}

// ---------------------------------------------------------------------------
// Split-bf16 MFMA GEMM over expanded basis (round-6 proven).
// ---------------------------------------------------------------------------
template <int CIN, int COUT, int HO, int WO, int SK>
__global__ __launch_bounds__(256, 2) void gemm_mfma(
    const uint32_t* __restrict__ E, const unsigned short* __restrict__ Bg,
    float* __restrict__ part) {
  constexpr int F = CIN * 9;
  constexpr int NKC = F / 16;
  constexpr int HI = HO / 2, WI = WO / 2;
  constexpr int M = BATCH * HO * WO;
  constexpr int CPB = NKC / SK;
  static_assert(NKC % SK == 0, "sk");

  __shared__ __align__(16) unsigned short lds[4 * 9216];

  const int t = threadIdx.x;
  const int mbase = blockIdx.x * 64;
  const int nb = blockIdx.y;
  const int kc0 = blockIdx.z * CPB;

  uint32_t ez[9];
  {
    float e0[9];
    expand9(0.f, e0);
#pragma unroll
    for (int v = 0; v < 9; ++v) ez[v] = packsplit(e0[v]);
  }

  const int lane = t & 63, wv_ = t >> 6;
  const int wm = wv_ >> 1, wn = wv_ & 1;
  const int frow = lane & 31, fkg = lane >> 5;
  const int aoff = ((wm * 32 + frow) * 16 + fkg * 8) * 2;  // bytes
  const int boff = ((wn * 32 + frow) * 16 + fkg * 8) * 2;

  f32x16 acc;
#pragma unroll
  for (int i = 0; i < 16; ++i) acc[i] = 0.f;

  for (int ci = 0; ci < CPB; ++ci) {
    const int kc = kc0 + ci;
    __syncthreads();

    // ---- stage A: 64 m x 16 fl ----
#pragma unroll
    for (int i = 0; i < 4; ++i) {
      int task = i * 256 + t;
      int ml = task >> 4, fl = task & 15;
      int f = kc * 16 + fl;
      int c = f / 9, r = f - 9 * c;
      int kh = r / 3, kw = r - kh * 3;
      int m = mbase + ml;
      int b = m / (HO * WO), hw2 = m % (HO * WO);
      int hh = hw2 / WO, ww = hw2 % WO;
      int hp = hh + kh - 1, wp = ww + kw - 1;
      bool ok = (unsigned)hp < (unsigned)HO && (unsigned)wp < (unsigned)WO;
      uint32_t uv[9];
      if (ok) {
        const uint32_t* ep =
            E + (size_t)(((b * CIN + c) * HI + (hp >> 1)) * WI + (wp >> 1)) * 9;
#pragma unroll
        for (int v = 0; v < 9; ++v) uv[v] = ep[v];
      } else {
#pragma unroll
        for (int v = 0; v < 9; ++v) uv[v] = ez[v];
      }
      int base = ml * 16 + fl;
#pragma unroll
      for (int v = 0; v < 9; ++v) {
        lds[v * 1024 + base] = (unsigned short)(uv[v] & 0xffffu);
        lds[9216 + v * 1024 + base] = (unsigned short)(uv[v] >> 16);
      }
    }

    // ---- stage B: linear copy ----
    {
      const unsigned short* bsrc = Bg + (size_t)kc * (2 * 9 * COUT * 16);
#pragma unroll
      for (int g = 0; g < 9; ++g) {
        int u = g * 256 + t;
        int pl = (u >= 1152) ? 1 : 0;
        int rr = u - pl * 1152;
        int v = rr >> 7, q = rr & 127;
        int nl = q >> 1, half = q & 1;
        size_t srcE = (size_t)pl * (9 * COUT * 16) + (size_t)v * (COUT * 16) +
                      (size_t)(nb * 64 + nl) * 16 + half * 8;
        int dst = (2 + pl) * 9216 + v * 1024 + nl * 16 + half * 8;
        *reinterpret_cast<float4*>(&lds[dst]) =
            *reinterpret_cast<const float4*>(&bsrc[srcE]);
      }
    }
    __syncthreads();

    // ---- compute: 9 v-steps x 3 split-products ----
#pragma unroll
    for (int v = 0; v < 9; ++v) {
      const char* lb = reinterpret_cast<const char*>(lds);
      bf16x8 ah = *reinterpret_cast<const bf16x8*>(lb + v * 2048 + aoff);
      bf16x8 al = *reinterpret_cast<const bf16x8*>(lb + 18432 + v * 2048 + aoff);
      bf16x8 bh = *reinterpret_cast<const bf16x8*>(lb + 36864 + v * 2048 + boff);
      bf16x8 bl = *reinterpret_cast<const bf16x8*>(lb + 55296 + v * 2048 + boff);
      acc = __builtin_amdgcn_mfma_f32_32x32x16_bf16(ah, bh, acc, 0, 0, 0);
      acc = __builtin_amdgcn_mfma_f32_32x32x16_bf16(ah, bl, acc, 0, 0, 0);
      acc = __builtin_amdgcn_mfma_f32_32x32x16_bf16(al, bh, acc, 0, 0, 0);
    }
  }

  float* p = part + (size_t)blockIdx.z * M * COUT;
  const int gn = nb * 64 + wn * 32 + frow;
#pragma unroll
  for (int r = 0; r < 16; ++r) {
    int mlocal = (r & 3) + 8 * (r >> 2) + 4 * fkg;
    int gm = mbase + wm * 32 + mlocal;
    p[(size_t)gm * COUT + gn] = acc[r];
  }
}

// ---------------------------------------------------------------------------
template <int COUT, int HO, int WO>
__global__ __launch_bounds__(256) void reduce_pe_pack(
    const float* __restrict__ part, uint32_t* __restrict__ E, int SK) {
  constexpr int M = BATCH * HO * WO;
  int idx = blockIdx.x * 256 + threadIdx.x;
  int ww = idx % WO;
  int tmp = idx / WO;
  int hh = tmp % HO;
  tmp /= HO;
  int o = tmp % COUT;
  int b = tmp / COUT;
  int m = (b * HO + hh) * WO + ww;
  float s = 0.f;
  for (int k = 0; k < SK; ++k) s += part[((size_t)k * M + m) * COUT + o];
  float e[9];
  expand9(s, e);
  uint32_t* p = E + (size_t)idx * 9;
#pragma unroll
  for (int v = 0; v < 9; ++v) p[v] = packsplit(e[v]);
}

template <int COUT, int HO, int WO>
__global__ __launch_bounds__(256) void reduce_p(
    const float* __restrict__ part, float* __restrict__ act, int SK) {
  constexpr int M = BATCH * HO * WO;
  int idx = blockIdx.x * 256 + threadIdx.x;
  int ww = idx % WO;
  int tmp = idx / WO;
  int hh = tmp % HO;
  tmp /= HO;
  int o = tmp % COUT;
  int b = tmp / COUT;
  int m = (b * HO + hh) * WO + ww;
  float s = 0.f;
  for (int k = 0; k < SK; ++k) s += part[((size_t)k * M + m) * COUT + o];
  act[idx] = s;
}

// ---------------------------------------------------------------------------
// L4 weights, neighbor-pre-summed (round-9 prep, validated):
// Wn[cs][cl][pc][nb][v][o] = sum over taps mapping to neighbor nb under
// parity class pc of W[o, c, kh, kw, v].
// ---------------------------------------------------------------------------
__global__ __launch_bounds__(256) void prep_wnl4(
    const float* __restrict__ bw, const float* __restrict__ sw,
    const float* __restrict__ ss, float* __restrict__ Wn) {
  int idx = blockIdx.x * 256 + threadIdx.x;  // 64*4*4*27 = 27648
  if (idx >= 27648) return;
  int u = idx % 27;
  int o = u % 3, v = u / 3;
  int rest = idx / 27;
  int nb = rest & 3;
  rest >>= 2;
  int pc = rest & 3;
  rest >>= 2;
  int c = rest;  // 0..63
  int PH = pc >> 1, PW = pc & 1;
  int a = nb >> 1, b2 = nb & 1;
  float s = 0.f;
#pragma unroll
  for (int kh = 0; kh < 3; ++kh) {
    if (((kh > PH) ? 1 : 0) != a) continue;
#pragma unroll
    for (int kw = 0; kw < 3; ++kw) {
      if (((kw > PW) ? 1 : 0) != b2) continue;
      int f = c * 9 + kh * 3 + kw;
      float wv = (v == 0)
                     ? bw[o * 576 + f]
                     : sw[((size_t)(o * 576 + f)) * 8 + (v - 1)] * ss[o * 576 + f];
      s += wv;
    }
  }
  Wn[idx] = s;
}

// ---------------------------------------------------------------------------
// L4 v7: v5's proven spill-free skeleton (unroll-1 q loop, per-q acc[3],
// neighbor-at-a-time en[9]) + round-9's pre-summed weights (4 neighbors x
// 27 FMA instead of 9 taps x 27 FMA = 2.25x less compute, same loads).
// ---------------------------------------------------------------------------
template <int PH, int PW>
__device__ void l4v7_wave(const float* __restrict__ eLds,
                          const float* __restrict__ WnB,
                          const float* __restrict__ ez, int lane, int bb,
                          int cs, float* __restrict__ p4) {
  constexpr int PC = PH * 2 + PW;
  const int j = lane & 15;
  const int i0 = (lane >> 4) << 2;
#pragma unroll 1
  for (int q = 0; q < 4; ++q) {
    const int i = i0 + q;
    float acc[3] = {0.f, 0.f, 0.f};
#pragma unroll
    for (int a = 0; a < 2; ++a) {
      const int gi = i + PH - 1 + a;
      const bool vr = (unsigned)gi < 16u;
#pragma unroll
      for (int b2 = 0; b2 < 2; ++b2) {
        const int gj = j + PW - 1 + b2;
        const bool ok = vr && ((unsigned)gj < 16u);
        const int pp = ok ? (gi * 16 + gj) : 0;  // clamped safe address
        const int nbi = a * 2 + b2;
#pragma unroll
        for (int cl = 0; cl < 4; ++cl) {
          const float* ep = eLds + cl * 2304 + pp * 9;
          float en[9];
#pragma unroll
          for (int v = 0; v < 9; ++v) en[v] = ok ? ep[v] : ez[v];
          const float* wp = WnB + ((cl * 4 + PC) * 4 + nbi) * 27;
#pragma unroll
          for (int v = 0; v < 9; ++v) {
            acc[0] = fmaf(en[v], wp[v * 3 + 0], acc[0]);
            acc[1] = fmaf(en[v], wp[v * 3 + 1], acc[1]);
            acc[2] = fmaf(en[v], wp[v * 3 + 2], acc[2]);
          }
        }
      }
    }
    const int h = (i << 1) + PH, w = (j << 1) + PW;
#pragma unroll
    for (int o = 0; o < 3; ++o)
      p4[(size_t)cs * 196608 + ((bb * 3 + o) << 10) + (h << 5) + w] = acc[o];
  }
}

__global__ __launch_bounds__(256) void kan_l4_v7(
    const float* __restrict__ a3, const float* __restrict__ Wn,
    float* __restrict__ p4) {
  __shared__ float eLds[4 * 256 * 9];  // 36.9 KB
  const int bid = blockIdx.x;          // 64 bb x 16 cs
  const int bb = bid >> 4, cs = bid & 15;
  const int t = threadIdx.x;
  float ez[9];
  expand9(0.f, ez);
  // stage: expand 4 channels x 256 pixels (1 pixel/thread/channel)
#pragma unroll
  for (int cl = 0; cl < 4; ++cl) {
    float x = a3[(size_t)(bb * 64 + cs * 4 + cl) * 256 + t];
    float ev[9];
    expand9(x, ev);
#pragma unroll
    for (int v = 0; v < 9; ++v) eLds[(cl * 256 + t) * 9 + v] = ev[v];
  }
  __syncthreads();
  const int wv_ = t >> 6, lane = t & 63;
  const float* WnB = Wn + (size_t)cs * 4 * (4 * 4 * 27);
  if (wv_ == 0)
    l4v7_wave<0, 0>(eLds, WnB, ez, lane, bb, cs, p4);
  else if (wv_ == 1)
    l4v7_wave<0, 1>(eLds, WnB, ez, lane, bb, cs, p4);
  else if (wv_ == 2)
    l4v7_wave<1, 0>(eLds, WnB, ez, lane, bb, cs, p4);
  else
    l4v7_wave<1, 1>(eLds, WnB, ez, lane, bb, cs, p4);
}

__global__ __launch_bounds__(256) void reduce_tanh_l4_16(
    const float* __restrict__ p4, float* __restrict__ out) {
  int i = blockIdx.x * 256 + threadIdx.x;  // 196608
  float s = 0.f;
#pragma unroll
  for (int k = 0; k < 16; ++k) s += p4[(size_t)k * 196608 + i];
  out[i] = tanhf(s);
}

__global__ __launch_bounds__(256) void reduce_tanh_l4(
    const float* __restrict__ p4, float* __restrict__ out) {
  int i = blockIdx.x * 256 + threadIdx.x;
  float s = p4[i] + p4[i + 196608] + p4[i + 2 * 196608] + p4[i + 3 * 196608];
  out[i] = tanhf(s);
}

// ---------------------------------------------------------------------------
// Fallback path (round-1 proven) for small workspace
// ---------------------------------------------------------------------------
template <int CIN, int COUT, int HO, int WO, int BN, int SK>
__global__ __launch_bounds__(256) void kan_gemm(
    const float* __restrict__ in, const float* __restrict__ bw,
    const float* __restrict__ sw, const float* __restrict__ ss,
    float* __restrict__ outp) {
  constexpr int BM = 64, TM = 4, TN = 4, FC = 16;
  constexpr int F = CIN * 9;
  constexpr int HI = HO / 2, WI = WO / 2;
  constexpr int M = BATCH * HO * WO;
  constexpr int FPB = F / SK;

  __shared__ float Ae[FC * 9][BM];

  const int t = threadIdx.x;
  const int mbase = blockIdx.x * BM;
  const int obase = blockIdx.y * BN;
  const int f0 = blockIdx.z * FPB;

  const int cg = t & (BN / TN - 1);
  const int rg = t / (BN / TN);
  const int m0 = rg * TM;
  const int o0 = obase + cg * TN;

  float acc[TM][TN] = {};

  for (int fc = f0; fc < f0 + FPB; fc += FC) {
#pragma unroll
    for (int j = 0; j < BM * FC / 256; ++j) {
      int p = j * 256 + t;
      int ml = p & (BM - 1);
      int df = p >> 6;
      int f = fc + df;
      int c = f / 9;
      int r = f - c * 9;
      int kh = r / 3, kw = r - kh * 3;
      int m = mbase + ml;
      int bb = m / (HO * WO);
      int rem = m % (HO * WO);
      int hh = rem / WO, ww = rem % WO;
      int hp = hh + kh - 1, wp = ww + kw - 1;
      float val = 0.f;
      if (hp >= 0 && hp < HO && wp >= 0 && wp < WO)
        val = in[((bb * CIN + c) * HI + (hp >> 1)) * WI + (wp >> 1)];
      float e[9];
      expand9(val, e);
#pragma unroll
      for (int v = 0; v < 9; ++v) Ae[df * 9 + v][ml] = e[v];
    }
    __syncthreads();

#pragma unroll 2
    for (int df = 0; df < FC; ++df) {
      int f = fc + df;
      float wb[TN], wsv[TN][8];
#pragma unroll
      for (int tn = 0; tn < TN; ++tn) {
        int i = (o0 + tn) * F + f;
        wb[tn] = bw[i];
        float sc = ss[i];
        const float4* sp = reinterpret_cast<const float4*>(sw + (size_t)i * 8);
        float4 s0 = sp[0], s1 = sp[1];
        wsv[tn][0] = s0.x * sc; wsv[tn][1] = s0.y * sc;
        wsv[tn][2] = s0.z * sc; wsv[tn][3] = s0.w * sc;
        wsv[tn][4] = s1.x * sc; wsv[tn][5] = s1.y * sc;
        wsv[tn][6] = s1.z * sc; wsv[tn][7] = s1.w * sc;
      }
      float a[9][TM];
#pragma unroll
      for (int v = 0; v < 9; ++v) {
        float4 q = *reinterpret_cast<const float4*>(&Ae[df * 9 + v][m0]);
        a[v][0] = q.x; a[v][1] = q.y; a[v][2] = q.z; a[v][3] = q.w;
      }
#pragma unroll
      for (int tm = 0; tm < TM; ++tm)
#pragma unroll
        for (int tn = 0; tn < TN; ++tn) acc[tm][tn] += a[0][tm] * wb[tn];
#pragma unroll
      for (int v = 1; v < 9; ++v)
#pragma unroll
        for (int tm = 0; tm < TM; ++tm)
#pragma unroll
          for (int tn = 0; tn < TN; ++tn)
            acc[tm][tn] += a[v][tm] * wsv[tn][v - 1];
    }
    __syncthreads();
  }

  if constexpr (SK > 1) {
    float* p = outp + (size_t)blockIdx.z * M * COUT;
#pragma unroll
    for (int tm = 0; tm < TM; ++tm) {
      int m = mbase + m0 + tm;
#pragma unroll
      for (int tn = 0; tn < TN; ++tn)
        p[(size_t)m * COUT + (o0 + tn)] = acc[tm][tn];
    }
  } else {
#pragma unroll
    for (int tm = 0; tm < TM; ++tm) {
      int m = mbase + m0 + tm;
      int bb = m / (HO * WO);
      int rem = m % (HO * WO);
      int hh = rem / WO, ww = rem % WO;
#pragma unroll
      for (int tn = 0; tn < TN; ++tn) {
        int o = o0 + tn;
        outp[((bb * COUT + o) * HO + hh) * WO + ww] = acc[tm][tn];
      }
    }
  }
}

template <int COUT, int HO, int WO, int SK>
__global__ __launch_bounds__(256) void reduce_partials_old(
    const float* __restrict__ part, float* __restrict__ act) {
  constexpr int M = BATCH * HO * WO;
  int idx = blockIdx.x * 256 + threadIdx.x;
  if (idx >= M * COUT) return;
  float s = 0.f;
#pragma unroll
  for (int k = 0; k < SK; ++k) s += part[(size_t)k * M * COUT + idx];
  int m = idx / COUT, o = idx - (idx / COUT) * COUT;
  int bb = m / (HO * WO);
  int rem = m % (HO * WO);
  int hh = rem / WO, ww = rem % WO;
  act[((bb * COUT + o) * HO + hh) * WO + ww] = s;
}

__global__ __launch_bounds__(256) void kan_l4_split(
    const float* __restrict__ a3, const float* __restrict__ bw,
    const float* __restrict__ sw, const float* __restrict__ ss,
    float* __restrict__ p4) {
  int tid = blockIdx.x * 256 + threadIdx.x;
  int cs = tid >> 16, pix = tid & 65535;
  int b = pix >> 10, rem = pix & 1023, h = rem >> 5, w = rem & 31;
  float acc[3] = {0.f, 0.f, 0.f};
  for (int c = cs * 16; c < cs * 16 + 16; ++c) {
#pragma unroll
    for (int kh = 0; kh < 3; ++kh) {
#pragma unroll
      for (int kw = 0; kw < 3; ++kw) {
        int f = (c * 3 + kh) * 3 + kw;
        int hp = h + kh - 1, wp = w + kw - 1;
        float x = 0.f;
        if ((unsigned)hp < 32u && (unsigned)wp < 32u)
          x = a3[((b * 64 + c) * 16 + (hp >> 1)) * 16 + (wp >> 1)];
        float e[9];
        expand9(x, e);
#pragma unroll
        for (int o = 0; o < 3; ++o) {
          int i = o * 576 + f;
          float d = e[1] * sw[i * 8 + 0];
#pragma unroll
          for (int v = 1; v < 8; ++v) d += e[v + 1] * sw[i * 8 + v];
          acc[o] += e[0] * bw[i] + d * ss[i];
        }
      }
    }
  }
#pragma unroll
  for (int o = 0; o < 3; ++o)
    p4[cs * 196608 + ((b * 3 + o) << 10) + (h << 5) + w] = acc[o];
}

// ---------------------------------------------------------------------------
extern "C" void kernel_launch(void* const* d_in, const int* in_sizes, int n_in,
                              void* d_out, int out_size, void* d_ws,
                              size_t ws_size, hipStream_t stream) {
  const float* x     = (const float*)d_in[0];
  const float* lin_w = (const float*)d_in[1];
  const float* lin_b = (const float*)d_in[2];
  const float* bw1 = (const float*)d_in[3];
  const float* sw1 = (const float*)d_in[4];
  const float* ss1 = (const float*)d_in[5];
  const float* bw2 = (const float*)d_in[6];
  const float* sw2 = (const float*)d_in[7];
  const float* ss2 = (const float*)d_in[8];
  const float* bw3 = (const float*)d_in[9];
  const float* sw3 = (const float*)d_in[10];
  const float* ss3 = (const float*)d_in[11];
  const float* bw4 = (const float*)d_in[12];
  const float* sw4 = (const float*)d_in[13];
  const float* ss4 = (const float*)d_in[14];

  float* wsf = (float*)d_ws;
  float* h  = wsf;                        // 131072
  float* a1 = h + 131072;                 // 262144 (fallback only)
  float* a2 = a1 + 262144;                // 524288 (fallback only)
  float* a3 = a2 + 524288;                // 1048576, ends at 1966080
  // main-path regions
  unsigned short* Bg = (unsigned short*)(wsf + 1966080);  // 10,616,832 float-slots
  float* part = wsf + 1966080 + 10616832;                 // 2,097,152
  uint32_t* Eg = (uint32_t*)(wsf + 14680064);             // 4,718,592
  float* wl4 = h;                    // h dead on main path after linear (27648 floats)
  float* p4  = wsf + 1966080;        // 16*196608 = 3.1M, reuses Bg (dead post-L3)

  const size_t baseFloats = 1966080;
  size_t availFloats = ws_size / 4 > baseFloats ? ws_size / 4 - baseFloats : 0;
  const size_t mainNeed = 10616832ull + 2097152ull + 4718592ull;  // 17.4M

  if (availFloats >= mainNeed) {
    linear_pack_kernel<<<512, 256, 0, stream>>>(x, lin_w, lin_b, h, Eg, 1);

    // L1: CIN=512 COUT=256 4x4, SK=8
    prep_bpack<4608, 256><<<41472, 256, 0, stream>>>(bw1, sw1, ss1, Bg);
    gemm_mfma<512, 256, 4, 4, 8>
        <<<dim3(16, 4, 8), 256, 0, stream>>>(Eg, Bg, part);
    reduce_pe_pack<256, 4, 4><<<1024, 256, 0, stream>>>(part, Eg, 8);

    // L2: CIN=256 COUT=128 8x8, SK=4
    prep_bpack<2304, 128><<<10368, 256, 0, stream>>>(bw2, sw2, ss2, Bg);
    gemm_mfma<256, 128, 8, 8, 4>
        <<<dim3(64, 2, 4), 256, 0, stream>>>(Eg, Bg, part);
    reduce_pe_pack<128, 8, 8><<<2048, 256, 0, stream>>>(part, Eg, 4);

    // L3: CIN=128 COUT=64 16x16, SK=2
    prep_bpack<1152, 64><<<2592, 256, 0, stream>>>(bw3, sw3, ss3, Bg);
    gemm_mfma<128, 64, 16, 16, 2>
        <<<dim3(256, 1, 2), 256, 0, stream>>>(Eg, Bg, part);
    reduce_p<64, 16, 16><<<4096, 256, 0, stream>>>(part, a3, 2);

    // L4: fused LDS expansion + pre-summed weights in v5's spill-free skeleton
    prep_wnl4<<<108, 256, 0, stream>>>(bw4, sw4, ss4, wl4);
    kan_l4_v7<<<1024, 256, 0, stream>>>(a3, wl4, p4);
    reduce_tanh_l4_16<<<768, 256, 0, stream>>>(p4, (float*)d_out);
  } else {
    // round-1 proven fallback (needs ~16.3 MB)
    float* partOld = a3 + 1048576;
    linear_pack_kernel<<<512, 256, 0, stream>>>(x, lin_w, lin_b, h, nullptr, 0);
    kan_gemm<512, 256, 4, 4, 64, 8>
        <<<dim3(16, 4, 8), 256, 0, stream>>>(h, bw1, sw1, ss1, partOld);
    reduce_partials_old<256, 4, 4, 8><<<1024, 256, 0, stream>>>(partOld, a1);
    kan_gemm<256, 128, 8, 8, 64, 2>
        <<<dim3(64, 2, 2), 256, 0, stream>>>(a1, bw2, sw2, ss2, partOld);
    reduce_partials_old<128, 8, 8, 2><<<2048, 256, 0, stream>>>(partOld, a2);
    kan_gemm<128, 64, 16, 16, 64, 1>
        <<<dim3(256, 1, 1), 256, 0, stream>>>(a2, bw3, sw3, ss3, a3);
    kan_l4_split<<<1024, 256, 0, stream>>>(a3, bw4, sw4, ss4, partOld);
    reduce_tanh_l4<<<768, 256, 0, stream>>>(partOld, (float*)d_out);
  }
}